// Round 1
// baseline (228.976 us; speedup 1.0000x reference)
//
#include <hip/hip_runtime.h>

#define S 7
#define NB 2
#define NC 80
#define NBOX 20
#define CELLS (S*S)            // 49
#define CH (5+NC)              // 85
#define PER_B (CELLS*NB*CH)    // 8330 floats per batch image
#define L_COORD 5.0f
#define L_NOOBJ 0.5f

__global__ __launch_bounds__(256) void yolo_loss_kernel(
    const float* __restrict__ pred,
    const float* __restrict__ boxes,
    const int*   __restrict__ labels,
    float*       __restrict__ out,
    float inv_B)
{
    __shared__ int   s_winner[CELLS];
    __shared__ float s_cx[NBOX], s_cy[NBOX], s_w[NBOX], s_h[NBOX];
    __shared__ int   s_lab[NBOX];
    __shared__ float s_tx[CELLS], s_ty[CELLS], s_tw[CELLS], s_th[CELLS];
    __shared__ int   s_label[CELLS];
    __shared__ int   s_resp[CELLS];   // -1 = no object, else responsible box 0/1
    __shared__ float s_wsum[4];

    const int b   = blockIdx.x;
    const int tid = threadIdx.x;

    if (tid < CELLS) s_winner[tid] = NBOX;
    __syncthreads();

    // Phase A: boxes -> cells, winner = min box index per cell
    if (tid < NBOX) {
        const float* bx = boxes + ((size_t)b * NBOX + tid) * 4;
        float x1 = bx[0], y1 = bx[1], x2 = bx[2], y2 = bx[3];
        float x = (x1 + x2) * 0.5f, y = (y1 + y2) * 0.5f;
        float w = x2 - x1,          h = y2 - y1;
        int j = (int)floorf(x * (float)S); j = min(max(j, 0), S - 1);
        int i = (int)floorf(y * (float)S); i = min(max(i, 0), S - 1);
        s_cx[tid] = x; s_cy[tid] = y; s_w[tid] = w; s_h[tid] = h;
        s_lab[tid] = labels[(size_t)b * NBOX + tid];
        atomicMin(&s_winner[i * S + j], tid);
    }
    __syncthreads();

    // Phase B: per-cell target feats + responsible-box (IoU argmax, first-wins tie)
    if (tid < CELLS) {
        int w = s_winner[tid];
        if (w < NBOX) {
            int i = tid / S, j = tid - (tid / S) * S;
            float x = s_cx[w], y = s_cy[w];
            float tx = x * (float)S - (float)j;
            float ty = y * (float)S - (float)i;
            float tw = s_w[w], th = s_h[w];
            s_tx[tid] = tx; s_ty[tid] = ty; s_tw[tid] = tw; s_th[tid] = th;
            s_label[tid] = s_lab[w];

            const float* p = pred + ((size_t)b * CELLS + tid) * (NB * CH);
            float iou[2];
            float bx1 = tx - tw * 0.5f, by1 = ty - th * 0.5f;
            float bx2 = tx + tw * 0.5f, by2 = ty + th * 0.5f;
            float barea = (bx2 - bx1) * (by2 - by1);
            #pragma unroll
            for (int nb = 0; nb < NB; nb++) {
                float px = p[nb * CH + 0], py = p[nb * CH + 1];
                float pw = p[nb * CH + 2], ph = p[nb * CH + 3];
                float ax1 = px - pw * 0.5f, ay1 = py - ph * 0.5f;
                float ax2 = px + pw * 0.5f, ay2 = py + ph * 0.5f;
                float iw = fmaxf(fminf(ax2, bx2) - fmaxf(ax1, bx1), 0.0f);
                float ih = fmaxf(fminf(ay2, by2) - fmaxf(ay1, by1), 0.0f);
                float inter = iw * ih;
                float uni = (ax2 - ax1) * (ay2 - ay1) + barea - inter;
                iou[nb] = inter / (uni + 1e-6f);
            }
            s_resp[tid] = (iou[1] > iou[0]) ? 1 : 0;
        } else {
            s_resp[tid] = -1;
            s_tx[tid] = 0.f; s_ty[tid] = 0.f; s_tw[tid] = 0.f; s_th[tid] = 0.f;
            s_label[tid] = 0;
        }
    }
    __syncthreads();

    // Phase C: single coalesced float2 pass over predictions[b]
    float acc = 0.0f;
    const float2* p2 = (const float2*)(pred + (size_t)b * PER_B);
    for (int e = tid; e < PER_B / 2; e += 256) {
        float2 v = p2[e];
        int f = 2 * e;
        #pragma unroll
        for (int k = 0; k < 2; k++) {
            int ff = f + k;
            float p = (k == 0) ? v.x : v.y;
            int c  = ff / (NB * CH);
            int r  = ff - c * (NB * CH);
            int nb = (r >= CH) ? 1 : 0;
            int ch = r - nb * CH;
            int resp = s_resp[c];
            if (resp < 0) {
                if (ch == 4) acc += L_NOOBJ * p * p;      // no-object conf
            } else if (nb == resp) {
                if (ch >= 5) {                             // class term
                    float t = (ch - 5 == s_label[c]) ? 1.0f : 0.0f;
                    float d = p - t; acc += d * d;
                } else if (ch == 4) {                      // obj conf (tconf = 1)
                    float d = p - 1.0f; acc += d * d;
                } else if (ch < 2) {                       // xy
                    float t = (ch == 0) ? s_tx[c] : s_ty[c];
                    float d = p - t; acc += L_COORD * d * d;
                } else {                                   // wh (sqrt space)
                    float t = (ch == 2) ? s_tw[c] : s_th[c];
                    float d = sqrtf(fmaxf(p, 1e-6f)) - sqrtf(fmaxf(t, 1e-6f));
                    acc += L_COORD * d * d;
                }
            }
        }
    }

    // wave-64 reduce, then cross-wave via LDS
    #pragma unroll
    for (int off = 32; off > 0; off >>= 1) acc += __shfl_down(acc, off, 64);
    int lane = tid & 63, wv = tid >> 6;
    if (lane == 0) s_wsum[wv] = acc;
    __syncthreads();
    if (tid == 0) {
        float s = s_wsum[0] + s_wsum[1] + s_wsum[2] + s_wsum[3];
        atomicAdd(out, s * inv_B);
    }
}

extern "C" void kernel_launch(void* const* d_in, const int* in_sizes, int n_in,
                              void* d_out, int out_size, void* d_ws, size_t ws_size,
                              hipStream_t stream) {
    const float* pred   = (const float*)d_in[0];
    const float* boxes  = (const float*)d_in[1];
    const int*   labels = (const int*)d_in[2];
    float* out = (float*)d_out;

    const int B = in_sizes[0] / PER_B;   // 4096

    // d_out is re-poisoned to 0xAA before every replay — zero it on-stream.
    hipMemsetAsync(d_out, 0, sizeof(float) * out_size, stream);
    yolo_loss_kernel<<<B, 256, 0, stream>>>(pred, boxes, labels, out, 1.0f / (float)B);
}

// Round 2
// 215.592 us; speedup vs baseline: 1.0621x; 1.0621x over previous
//
#include <hip/hip_runtime.h>

#define S 7
#define NB 2
#define NC 80
#define NBOX 20
#define CELLS (S*S)            // 49
#define CH (5+NC)              // 85
#define PAIR (NB*CH)           // 170
#define PER_B (CELLS*PAIR)     // 8330 floats per batch image
#define NIT (PER_B/2)          // 4165 float2 per batch image
#define L_COORD 5.0f
#define L_NOOBJ 0.5f

// Branchless loss for one float2 (both elements always in the same cell:
// cell boundaries are multiples of 170 (even), float2 starts are even).
__device__ __forceinline__ float pair_loss(float2 v, int ff,
                                           const int* __restrict__ s_meta,
                                           const float* __restrict__ s_coord)
{
    unsigned c = (unsigned)ff / (unsigned)PAIR;   // magic-mul
    int r0 = ff - (int)c * PAIR;
    int meta = s_meta[c];
    int respp1 = meta >> 8;          // 0 = no object, else resp+1 (1 or 2)
    int label  = meta & 0xff;
    bool noobj = (respp1 == 0);

    float acc = 0.0f;
    #pragma unroll
    for (int k = 0; k < 2; ++k) {
        float p = k ? v.y : v.x;
        int r  = r0 + k;
        int nb = (r >= CH) ? 1 : 0;
        int ch = r - nb * CH;

        bool isresp = ((nb + 1) == respp1);
        float t_box = s_coord[4u * c + (ch & 3)];   // tx,ty,sqrt(tw),sqrt(th)
        float t = (ch >= 5) ? ((ch - 5 == label) ? 1.0f : 0.0f)
                : (ch == 4) ? 1.0f
                : t_box;
        float q = (ch == 2 || ch == 3) ? sqrtf(fmaxf(p, 1e-6f)) : p;

        float m_obj = isresp ? ((ch < 4) ? L_COORD : 1.0f) : 0.0f;
        float m_no  = (ch == 4) ? L_NOOBJ : 0.0f;
        float m = noobj ? m_no : m_obj;
        t = noobj ? 0.0f : t;
        // noobj contributions only occur at ch==4 where q==p already.

        float d = q - t;
        acc += m * d * d;
    }
    return acc;
}

__global__ __launch_bounds__(256) void yolo_loss_kernel(
    const float* __restrict__ pred,
    const float* __restrict__ boxes,
    const int*   __restrict__ labels,
    float*       __restrict__ out,
    float inv_B)
{
    __shared__ int   s_winner[CELLS];
    __shared__ float s_cx[NBOX], s_cy[NBOX], s_w[NBOX], s_h[NBOX];
    __shared__ int   s_lab[NBOX];
    __shared__ int   s_meta[CELLS];       // (resp+1)<<8 | label; 0<<8 = no object
    __shared__ float s_coord[CELLS * 4];  // tx, ty, sqrt(tw), sqrt(th)
    __shared__ float s_wsum[4];

    const int b   = blockIdx.x;
    const int tid = threadIdx.x;

    if (tid < CELLS) s_winner[tid] = NBOX;
    __syncthreads();

    // Phase A: boxes -> cells, winner = min box index per cell
    if (tid < NBOX) {
        const float* bx = boxes + ((size_t)b * NBOX + tid) * 4;
        float x1 = bx[0], y1 = bx[1], x2 = bx[2], y2 = bx[3];
        float x = (x1 + x2) * 0.5f, y = (y1 + y2) * 0.5f;
        float w = x2 - x1,          h = y2 - y1;
        int j = (int)floorf(x * (float)S); j = min(max(j, 0), S - 1);
        int i = (int)floorf(y * (float)S); i = min(max(i, 0), S - 1);
        s_cx[tid] = x; s_cy[tid] = y; s_w[tid] = w; s_h[tid] = h;
        s_lab[tid] = labels[(size_t)b * NBOX + tid];
        atomicMin(&s_winner[i * S + j], tid);
    }
    __syncthreads();

    // Phase B: per-cell target feats + responsible box (IoU argmax, first-wins)
    if (tid < CELLS) {
        int w = s_winner[tid];
        if (w < NBOX) {
            int i = tid / S, j = tid - (tid / S) * S;
            float x = s_cx[w], y = s_cy[w];
            float tx = x * (float)S - (float)j;
            float ty = y * (float)S - (float)i;
            float tw = s_w[w], th = s_h[w];
            s_coord[4 * tid + 0] = tx;
            s_coord[4 * tid + 1] = ty;
            s_coord[4 * tid + 2] = sqrtf(fmaxf(tw, 1e-6f));
            s_coord[4 * tid + 3] = sqrtf(fmaxf(th, 1e-6f));

            const float* p = pred + ((size_t)b * CELLS + tid) * PAIR;
            float iou[2];
            float bx1 = tx - tw * 0.5f, by1 = ty - th * 0.5f;
            float bx2 = tx + tw * 0.5f, by2 = ty + th * 0.5f;
            float barea = (bx2 - bx1) * (by2 - by1);
            #pragma unroll
            for (int nb = 0; nb < NB; nb++) {
                float px = p[nb * CH + 0], py = p[nb * CH + 1];
                float pw = p[nb * CH + 2], ph = p[nb * CH + 3];
                float ax1 = px - pw * 0.5f, ay1 = py - ph * 0.5f;
                float ax2 = px + pw * 0.5f, ay2 = py + ph * 0.5f;
                float iw = fmaxf(fminf(ax2, bx2) - fmaxf(ax1, bx1), 0.0f);
                float ih = fmaxf(fminf(ay2, by2) - fmaxf(ay1, by1), 0.0f);
                float inter = iw * ih;
                float uni = (ax2 - ax1) * (ay2 - ay1) + barea - inter;
                iou[nb] = inter / (uni + 1e-6f);
            }
            int resp = (iou[1] > iou[0]) ? 1 : 0;
            s_meta[tid] = ((resp + 1) << 8) | s_lab[w];
        } else {
            s_meta[tid] = 0;
            s_coord[4 * tid + 0] = 0.f; s_coord[4 * tid + 1] = 0.f;
            s_coord[4 * tid + 2] = 0.f; s_coord[4 * tid + 3] = 0.f;
        }
    }
    __syncthreads();

    // Phase C: coalesced float2 pass, 4 loads in flight, branchless math.
    float acc = 0.0f;
    const float2* p2 = (const float2*)(pred + (size_t)b * PER_B);
    #pragma unroll
    for (int k = 0; k < 4; ++k) {
        int e = tid + k * 1024;
        float2 v0 = p2[e];
        float2 v1 = p2[e + 256];
        float2 v2 = p2[e + 512];
        float2 v3 = p2[e + 768];
        acc += pair_loss(v0, 2 * e,          s_meta, s_coord);
        acc += pair_loss(v1, 2 * (e + 256),  s_meta, s_coord);
        acc += pair_loss(v2, 2 * (e + 512),  s_meta, s_coord);
        acc += pair_loss(v3, 2 * (e + 768),  s_meta, s_coord);
    }
    {   // remainder: elements [4096, 4165)
        int e = 4096 + tid;
        if (e < NIT) acc += pair_loss(p2[e], 2 * e, s_meta, s_coord);
    }

    // wave-64 reduce, then cross-wave via LDS
    #pragma unroll
    for (int off = 32; off > 0; off >>= 1) acc += __shfl_down(acc, off, 64);
    int lane = tid & 63, wv = tid >> 6;
    if (lane == 0) s_wsum[wv] = acc;
    __syncthreads();
    if (tid == 0) {
        float s = s_wsum[0] + s_wsum[1] + s_wsum[2] + s_wsum[3];
        atomicAdd(out, s * inv_B);
    }
}

extern "C" void kernel_launch(void* const* d_in, const int* in_sizes, int n_in,
                              void* d_out, int out_size, void* d_ws, size_t ws_size,
                              hipStream_t stream) {
    const float* pred   = (const float*)d_in[0];
    const float* boxes  = (const float*)d_in[1];
    const int*   labels = (const int*)d_in[2];
    float* out = (float*)d_out;

    const int B = in_sizes[0] / PER_B;   // 4096

    // d_out is re-poisoned to 0xAA before every replay — zero it on-stream.
    hipMemsetAsync(d_out, 0, sizeof(float) * out_size, stream);
    yolo_loss_kernel<<<B, 256, 0, stream>>>(pred, boxes, labels, out, 1.0f / (float)B);
}

// Round 3
// 213.903 us; speedup vs baseline: 1.0705x; 1.0079x over previous
//
#include <hip/hip_runtime.h>

#define S 7
#define NB 2
#define NC 80
#define NBOX 20
#define CELLS 49
#define CH 85              // 5 + NC
#define PAIR 170           // NB*CH
#define PER_B 8330         // CELLS*PAIR floats per image
#define N4 4165            // float4 per 2 images (16660 floats / 4)
#define L_COORD 5.0f
#define L_NOOBJ 0.5f

// Streaming-pass element: acc += w * p^2, w from per-(cell,box,cat) LDS table.
// cat: 0 = box coords (xy/wh, handled in Phase B -> w=0), 1 = conf, 2 = class.
__device__ __forceinline__ float elem1(float p, unsigned c, int r,
                                       const float* __restrict__ wt)
{
    int nb  = (r >= CH) ? 1 : 0;
    int rr  = r - nb * CH;
    int cat = (rr >= 4) + (rr >= 5);
    float w = wt[c * 8u + (unsigned)(nb * 4 + cat)];
    return w * p * p;
}

// One float4 = 4 consecutive floats; starts at ff = 4e (even r0), so the only
// possible cell straddle is between the two float2 halves (r0 == 168).
__device__ __forceinline__ float elem4(float4 v, int e,
                                       const float* __restrict__ wt)
{
    unsigned ff = 4u * (unsigned)e;
    unsigned c0 = ff / (unsigned)PAIR;          // compiler magic-mul
    int r0 = (int)(ff - c0 * (unsigned)PAIR);   // even
    int wrap = (r0 == PAIR - 2) ? 1 : 0;
    unsigned c1 = c0 + (unsigned)wrap;
    int r2 = wrap ? 0 : r0 + 2;
    float a;
    a  = elem1(v.x, c0, r0,     wt);
    a += elem1(v.y, c0, r0 + 1, wt);
    a += elem1(v.z, c1, r2,     wt);
    a += elem1(v.w, c1, r2 + 1, wt);
    return a;
}

__global__ __launch_bounds__(256) void yolo_loss_kernel(
    const float* __restrict__ pred,
    const float* __restrict__ boxes,
    const int*   __restrict__ labels,
    float*       __restrict__ out,
    float inv_B)
{
    __shared__ int   s_winner[2 * CELLS];
    __shared__ float s_cx[2 * NBOX], s_cy[2 * NBOX], s_bw[2 * NBOX], s_bh[2 * NBOX];
    __shared__ int   s_lab[2 * NBOX];
    __shared__ float s_wt[2 * CELLS * 8];   // [cell][nb][cat] weight table
    __shared__ float s_wsum[4];

    const int b0  = blockIdx.x * 2;         // two images per block
    const int tid = threadIdx.x;

    if (tid < 2 * CELLS) s_winner[tid] = NBOX;
    __syncthreads();

    // ---- Phase A: 40 boxes (2 images), winner = min box index per cell ----
    if (tid < 2 * NBOX) {
        int img = (tid >= NBOX) ? 1 : 0;
        const float* bx = boxes + ((size_t)(b0 + img) * NBOX + (tid - img * NBOX)) * 4;
        float x1 = bx[0], y1 = bx[1], x2 = bx[2], y2 = bx[3];
        float x = (x1 + x2) * 0.5f, y = (y1 + y2) * 0.5f;
        s_cx[tid] = x; s_cy[tid] = y;
        s_bw[tid] = x2 - x1; s_bh[tid] = y2 - y1;
        s_lab[tid] = labels[(size_t)(b0 + img) * NBOX + (tid - img * NBOX)];
        int j = (int)floorf(x * (float)S); j = min(max(j, 0), S - 1);
        int i = (int)floorf(y * (float)S); i = min(max(i, 0), S - 1);
        atomicMin(&s_winner[img * CELLS + i * S + j], tid - img * NBOX);
    }
    __syncthreads();

    // ---- Phase B: per-cell — responsible box, weight table, correction ----
    float acc = 0.0f;   // Phase-B correction folds into the reduction
    if (tid < 2 * CELLS) {
        int img  = (tid >= CELLS) ? 1 : 0;
        int cell = tid - img * CELLS;
        int w    = s_winner[tid];
        int base = tid * 8;
        if (w < NBOX) {
            int i = cell / S, j = cell - (cell / S) * S;
            int bi = img * NBOX + w;
            float x = s_cx[bi], y = s_cy[bi];
            float tx = x * (float)S - (float)j;
            float ty = y * (float)S - (float)i;
            float tw = s_bw[bi], th = s_bh[bi];

            const float* p = pred + ((size_t)(b0 + img) * CELLS + cell) * PAIR;
            float bx1 = tx - tw * 0.5f, by1 = ty - th * 0.5f;
            float bx2 = tx + tw * 0.5f, by2 = ty + th * 0.5f;
            float barea = (bx2 - bx1) * (by2 - by1);
            float iou[2], px[2], py[2], pw[2], ph[2];
            #pragma unroll
            for (int nb = 0; nb < NB; nb++) {
                px[nb] = p[nb * CH + 0]; py[nb] = p[nb * CH + 1];
                pw[nb] = p[nb * CH + 2]; ph[nb] = p[nb * CH + 3];
                float ax1 = px[nb] - pw[nb] * 0.5f, ay1 = py[nb] - ph[nb] * 0.5f;
                float ax2 = px[nb] + pw[nb] * 0.5f, ay2 = py[nb] + ph[nb] * 0.5f;
                float iw = fmaxf(fminf(ax2, bx2) - fmaxf(ax1, bx1), 0.0f);
                float ih = fmaxf(fminf(ay2, by2) - fmaxf(ay1, by1), 0.0f);
                float inter = iw * ih;
                float uni = (ax2 - ax1) * (ay2 - ay1) + barea - inter;
                iou[nb] = inter / (uni + 1e-6f);
            }
            int resp = (iou[1] > iou[0]) ? 1 : 0;
            int oth  = 1 - resp;

            // weight table: resp box {0,1,1}, other box {0,0,0}
            s_wt[base + resp * 4 + 0] = 0.0f;
            s_wt[base + resp * 4 + 1] = 1.0f;
            s_wt[base + resp * 4 + 2] = 1.0f;
            s_wt[base + oth  * 4 + 0] = 0.0f;
            s_wt[base + oth  * 4 + 1] = 0.0f;
            s_wt[base + oth  * 4 + 2] = 0.0f;

            // corrections: xy/wh in full, conf (1-2p), class (1-2p_label)
            float pc = p[resp * CH + 4];
            float pl = p[resp * CH + 5 + s_lab[bi]];
            float dx = px[resp] - tx, dy = py[resp] - ty;
            float dw = sqrtf(fmaxf(pw[resp], 1e-6f)) - sqrtf(fmaxf(tw, 1e-6f));
            float dh = sqrtf(fmaxf(ph[resp], 1e-6f)) - sqrtf(fmaxf(th, 1e-6f));
            acc = L_COORD * (dx * dx + dy * dy + dw * dw + dh * dh)
                + (1.0f - 2.0f * pc)      // (p-1)^2 = p^2 + (1-2p)
                + (1.0f - 2.0f * pl);     // sum(p-onehot)^2 = sum p^2 + (1-2p_l)
        } else {
            // no object: only conf channels at LAMBDA_NOOBJ
            s_wt[base + 0] = 0.0f; s_wt[base + 1] = L_NOOBJ; s_wt[base + 2] = 0.0f;
            s_wt[base + 4] = 0.0f; s_wt[base + 5] = L_NOOBJ; s_wt[base + 6] = 0.0f;
        }
    }
    __syncthreads();

    // ---- Phase C: coalesced float4 stream over 2 images ----
    const float4* p4 = (const float4*)(pred + (size_t)b0 * PER_B);
    #pragma unroll
    for (int k = 0; k < 16; ++k) {
        int e = tid + k * 256;
        float4 v = p4[e];
        acc += elem4(v, e, s_wt);
    }
    {   // remainder: e in [4096, 4165)
        int e = 4096 + tid;
        if (e < N4) acc += elem4(p4[e], e, s_wt);
    }

    // ---- reduce: wave-64 shuffle, cross-wave LDS, one atomic per block ----
    #pragma unroll
    for (int off = 32; off > 0; off >>= 1) acc += __shfl_down(acc, off, 64);
    int lane = tid & 63, wv = tid >> 6;
    if (lane == 0) s_wsum[wv] = acc;
    __syncthreads();
    if (tid == 0) {
        float s = s_wsum[0] + s_wsum[1] + s_wsum[2] + s_wsum[3];
        atomicAdd(out, s * inv_B);
    }
}

extern "C" void kernel_launch(void* const* d_in, const int* in_sizes, int n_in,
                              void* d_out, int out_size, void* d_ws, size_t ws_size,
                              hipStream_t stream) {
    const float* pred   = (const float*)d_in[0];
    const float* boxes  = (const float*)d_in[1];
    const int*   labels = (const int*)d_in[2];

    const int B = in_sizes[0] / PER_B;   // 4096

    // d_out is re-poisoned to 0xAA before every replay — zero it on-stream.
    hipMemsetAsync(d_out, 0, sizeof(float) * out_size, stream);
    yolo_loss_kernel<<<B / 2, 256, 0, stream>>>(pred, boxes, labels,
                                                (float*)d_out, 1.0f / (float)B);
}

// Round 4
// 201.860 us; speedup vs baseline: 1.1343x; 1.0597x over previous
//
#include <hip/hip_runtime.h>

#define S 7
#define NB 2
#define NC 80
#define NBOX 20
#define CELLS 49
#define CH 85                  // 5 + NC
#define PAIR 170               // NB*CH
#define PER_B 8330             // CELLS*PAIR floats per image
#define NIMG 4096
#define NCELL_TOT (NIMG*CELLS)           // 200704 cells
#define N4TOT (NIMG*PER_B/4)             // 8529920 float4s
#define PREP_IMGS 4
#define PREP_BLOCKS (NIMG/PREP_IMGS)     // 1024
#define STREAM_BLOCKS 2048
#define TSTRIDE (STREAM_BLOCKS*256)      // 524288
#define L_COORD 5.0f
#define L_NOOBJ 0.5f

// ---------------- block reduce helper (256 threads) ----------------
__device__ __forceinline__ void block_reduce_store(float acc, float* dst)
{
    __shared__ float s_wsum[4];
    int tid = threadIdx.x;
    #pragma unroll
    for (int off = 32; off > 0; off >>= 1) acc += __shfl_down(acc, off, 64);
    int lane = tid & 63, wv = tid >> 6;
    if (lane == 0) s_wsum[wv] = acc;
    __syncthreads();
    if (tid == 0) *dst = s_wsum[0] + s_wsum[1] + s_wsum[2] + s_wsum[3];
}

// ---------------- kernel 1: per-cell weight table + corrections ----------------
__global__ __launch_bounds__(256) void prep_kernel(
    const float* __restrict__ pred,
    const float* __restrict__ boxes,
    const int*   __restrict__ labels,
    float4*      __restrict__ wt4,      // [NIMG*CELLS]
    float*       __restrict__ partial)  // [PREP_BLOCKS]
{
    __shared__ int   s_winner[PREP_IMGS * CELLS];
    __shared__ float s_cx[PREP_IMGS * NBOX], s_cy[PREP_IMGS * NBOX];
    __shared__ float s_bw[PREP_IMGS * NBOX], s_bh[PREP_IMGS * NBOX];
    __shared__ int   s_lab[PREP_IMGS * NBOX];

    const int b0  = blockIdx.x * PREP_IMGS;
    const int tid = threadIdx.x;

    if (tid < PREP_IMGS * CELLS) s_winner[tid] = NBOX;
    __syncthreads();

    // Phase A: 80 boxes (4 images) -> cells, winner = min box index per cell
    if (tid < PREP_IMGS * NBOX) {
        int img = tid / NBOX, bxi = tid - img * NBOX;
        const float* bx = boxes + ((size_t)(b0 + img) * NBOX + bxi) * 4;
        float x1 = bx[0], y1 = bx[1], x2 = bx[2], y2 = bx[3];
        float x = (x1 + x2) * 0.5f, y = (y1 + y2) * 0.5f;
        s_cx[tid] = x; s_cy[tid] = y;
        s_bw[tid] = x2 - x1; s_bh[tid] = y2 - y1;
        s_lab[tid] = labels[(size_t)(b0 + img) * NBOX + bxi];
        int j = (int)floorf(x * (float)S); j = min(max(j, 0), S - 1);
        int i = (int)floorf(y * (float)S); i = min(max(i, 0), S - 1);
        atomicMin(&s_winner[img * CELLS + i * S + j], bxi);
    }
    __syncthreads();

    // Phase B: responsible box per cell, weight quad to global, corrections
    float acc = 0.0f;
    if (tid < PREP_IMGS * CELLS) {
        int img  = tid / CELLS;
        int cell = tid - img * CELLS;
        int w    = s_winner[tid];
        float4 wq;
        if (w < NBOX) {
            int i = cell / S, j = cell - (cell / S) * S;
            int bi = img * NBOX + w;
            float x = s_cx[bi], y = s_cy[bi];
            float tx = x * (float)S - (float)j;
            float ty = y * (float)S - (float)i;
            float tw = s_bw[bi], th = s_bh[bi];

            const float* p = pred + ((size_t)(b0 + img) * CELLS + cell) * PAIR;
            float bx1 = tx - tw * 0.5f, by1 = ty - th * 0.5f;
            float bx2 = tx + tw * 0.5f, by2 = ty + th * 0.5f;
            float barea = (bx2 - bx1) * (by2 - by1);
            float iou[2], px[2], py[2], pw[2], ph[2];
            #pragma unroll
            for (int nb = 0; nb < NB; nb++) {
                px[nb] = p[nb * CH + 0]; py[nb] = p[nb * CH + 1];
                pw[nb] = p[nb * CH + 2]; ph[nb] = p[nb * CH + 3];
                float ax1 = px[nb] - pw[nb] * 0.5f, ay1 = py[nb] - ph[nb] * 0.5f;
                float ax2 = px[nb] + pw[nb] * 0.5f, ay2 = py[nb] + ph[nb] * 0.5f;
                float iw = fmaxf(fminf(ax2, bx2) - fmaxf(ax1, bx1), 0.0f);
                float ih = fmaxf(fminf(ay2, by2) - fmaxf(ay1, by1), 0.0f);
                float inter = iw * ih;
                float uni = (ax2 - ax1) * (ay2 - ay1) + barea - inter;
                iou[nb] = inter / (uni + 1e-6f);
            }
            int resp = (iou[1] > iou[0]) ? 1 : 0;
            // quad = {wconf_box0, wcls_box0, wconf_box1, wcls_box1}
            wq = (resp == 0) ? make_float4(1.f, 1.f, 0.f, 0.f)
                             : make_float4(0.f, 0.f, 1.f, 1.f);

            float pc = p[resp * CH + 4];
            float pl = p[resp * CH + 5 + s_lab[bi]];
            float dx = px[resp] - tx, dy = py[resp] - ty;
            float dw = sqrtf(fmaxf(pw[resp], 1e-6f)) - sqrtf(fmaxf(tw, 1e-6f));
            float dh = sqrtf(fmaxf(ph[resp], 1e-6f)) - sqrtf(fmaxf(th, 1e-6f));
            acc = L_COORD * (dx * dx + dy * dy + dw * dw + dh * dh)
                + (1.0f - 2.0f * pc)      // (p-1)^2 = p^2 + (1-2p)
                + (1.0f - 2.0f * pl);     // sum(p-onehot)^2 = sum p^2 + (1-2p_l)
        } else {
            wq = make_float4(L_NOOBJ, 0.f, L_NOOBJ, 0.f);
        }
        wt4[(size_t)(b0 + img) * CELLS + cell] = wq;
    }
    __syncthreads();
    block_reduce_store(acc, &partial[blockIdx.x]);
}

// ---------------- kernel 2: pure stream, acc += m * p^2 ----------------
__device__ __forceinline__ float elem1(float p, int r, float4 w)
{
    int nb = (r >= CH) ? 1 : 0;
    int rr = r - nb * CH;
    float wconf = nb ? w.z : w.x;
    float wcls  = nb ? w.w : w.y;
    float m = (rr >= 5) ? wcls : ((rr == 4) ? wconf : 0.0f);
    return m * p * p;
}

__device__ __forceinline__ float elem4(float4 v, int e,
                                       const float4* __restrict__ wt4)
{
    unsigned ff = 4u * (unsigned)e;
    unsigned c0 = ff / (unsigned)PAIR;          // magic-mul
    int r0 = (int)(ff - c0 * (unsigned)PAIR);   // even; straddle only at 168
    float4 w0 = wt4[c0];
    float4 w1 = w0;
    bool wrap = (r0 == PAIR - 2);
    if (wrap) w1 = wt4[c0 + 1];
    int r2 = wrap ? 0 : r0 + 2;
    float a;
    a  = elem1(v.x, r0,     w0);
    a += elem1(v.y, r0 + 1, w0);
    a += elem1(v.z, r2,     w1);
    a += elem1(v.w, r2 + 1, w1);
    return a;
}

__global__ __launch_bounds__(256) void stream_kernel(
    const float4* __restrict__ p4,
    const float4* __restrict__ wt4,
    float*        __restrict__ partial)   // [STREAM_BLOCKS]
{
    const int tid = threadIdx.x;
    const int gid = blockIdx.x * 256 + tid;

    float acc = 0.0f;
    int e = gid;
    #pragma unroll 8
    for (int k = 0; k < 16; ++k) {
        acc += elem4(p4[e], e, wt4);
        e += TSTRIDE;
    }
    if (e < N4TOT) acc += elem4(p4[e], e, wt4);   // tail: first 141312 threads

    block_reduce_store(acc, &partial[blockIdx.x]);
}

// ---------------- kernel 3: final reduce ----------------
__global__ __launch_bounds__(256) void reduce_kernel(
    const float* __restrict__ partial, int n,
    float* __restrict__ out, float inv_B)
{
    const int tid = threadIdx.x;
    float acc = 0.0f;
    for (int i = tid; i < n; i += 256) acc += partial[i];
    __shared__ float s_wsum[4];
    #pragma unroll
    for (int off = 32; off > 0; off >>= 1) acc += __shfl_down(acc, off, 64);
    int lane = tid & 63, wv = tid >> 6;
    if (lane == 0) s_wsum[wv] = acc;
    __syncthreads();
    if (tid == 0) out[0] = (s_wsum[0] + s_wsum[1] + s_wsum[2] + s_wsum[3]) * inv_B;
}

extern "C" void kernel_launch(void* const* d_in, const int* in_sizes, int n_in,
                              void* d_out, int out_size, void* d_ws, size_t ws_size,
                              hipStream_t stream) {
    const float* pred   = (const float*)d_in[0];
    const float* boxes  = (const float*)d_in[1];
    const int*   labels = (const int*)d_in[2];

    // workspace layout (floats): [wt4 table | prep partials | stream partials]
    float4* wt4          = (float4*)d_ws;
    float*  prep_part    = (float*)d_ws + (size_t)NCELL_TOT * 4;
    float*  stream_part  = prep_part + PREP_BLOCKS;

    prep_kernel<<<PREP_BLOCKS, 256, 0, stream>>>(pred, boxes, labels, wt4, prep_part);
    stream_kernel<<<STREAM_BLOCKS, 256, 0, stream>>>((const float4*)pred, wt4, stream_part);
    reduce_kernel<<<1, 256, 0, stream>>>(prep_part, PREP_BLOCKS + STREAM_BLOCKS,
                                         (float*)d_out, 1.0f / (float)NIMG);
}